// Round 1
// baseline (318.974 us; speedup 1.0000x reference)
//
#include <hip/hip_runtime.h>
#include <math.h>

// WassersteinLoss (debiased Sinkhorn divergence, p=1) on MI355X.
// x = weighted-cluster prediction per row (B values), y = target (B values).
// 15 averaged eps iterations + 1 extrapolation, each = 4 softmins over BxB
// implicit cost matrices |x_i - y_j|. State is 9*B floats (~72KB) -> cache
// resident; kernels are transcendental/VALU bound.

#define BLK 256

__device__ inline void lse_combine(float& m, float& a, float m2, float a2) {
    float M = fmaxf(m, m2);
    if (M == -INFINITY) { m = M; a = 0.f; return; }
    a = a * __expf(m - M) + a2 * __expf(m2 - M);
    m = M;
}

// One wave per row: x[row] = sum(relu(pred)*k) / max(||relu(pred)||, 1e-12).
// Also zeroes the 4 potential arrays (zero_base[0..zero_len)).
__global__ void prep_kernel(const float* __restrict__ pred, float* __restrict__ x,
                            float* __restrict__ zero_base, int zero_len,
                            int B, int K) {
    int tid = threadIdx.x;
    int gid = blockIdx.x * blockDim.x + tid;
    if (gid < zero_len) zero_base[gid] = 0.f;

    int lane = tid & 63;
    int row = blockIdx.x * (BLK / 64) + (tid >> 6);
    if (row >= B) return;
    const float* pr = pred + (size_t)row * K;
    float s2 = 0.f, wsum = 0.f;
    for (int k = lane; k < K; k += 64) {
        float v = pr[k];
        v = v > 0.f ? v : 0.f;
        s2   += v * v;
        wsum += v * (float)k;
    }
    for (int off = 32; off; off >>= 1) {
        s2   += __shfl_xor(s2, off);
        wsum += __shfl_xor(wsum, off);
    }
    if (lane == 0) x[row] = wsum / fmaxf(sqrtf(s2), 1e-12f);
}

// One block per (potential, row). pot: 0=ft, 1=gt, 2=f_aa, 3=g_bb.
// softmin(eps, C, h)_i = -eps * LSE_j( logw + h_j/eps - |xi - src_j|/eps )
__global__ void sink_iter_kernel(const float* __restrict__ x, const float* __restrict__ y,
                                 const float* __restrict__ fin, const float* __restrict__ gin,
                                 const float* __restrict__ fain, const float* __restrict__ gbin,
                                 float* __restrict__ fout, float* __restrict__ gout,
                                 float* __restrict__ faout, float* __restrict__ gbout,
                                 int B, float eps, float inv_eps, float logw, int avg) {
    int bid = blockIdx.x;
    int pot = bid / B;
    int row = bid - pot * B;

    const float* srcv; const float* h; float xi; float prev; float* outp;
    switch (pot) {
        case 0:  xi = x[row]; srcv = y; h = gin;  prev = fin[row];  outp = fout  + row; break;
        case 1:  xi = y[row]; srcv = x; h = fin;  prev = gin[row];  outp = gout  + row; break;
        case 2:  xi = x[row]; srcv = x; h = fain; prev = fain[row]; outp = faout + row; break;
        default: xi = y[row]; srcv = y; h = gbin; prev = gbin[row]; outp = gbout + row; break;
    }

    // online LSE over j
    float m = -INFINITY, acc = 0.f;
    for (int j = threadIdx.x; j < B; j += BLK) {
        float s = logw + (h[j] - fabsf(xi - srcv[j])) * inv_eps;
        float nm = fmaxf(m, s);
        acc = acc * __expf(m - nm) + __expf(s - nm);
        m = nm;
    }
    // wave reduce
    for (int off = 32; off; off >>= 1)
        lse_combine(m, acc, __shfl_xor(m, off), __shfl_xor(acc, off));
    __shared__ float sm[BLK / 64], sa[BLK / 64];
    int lane = threadIdx.x & 63, w = threadIdx.x >> 6;
    if (lane == 0) { sm[w] = m; sa[w] = acc; }
    __syncthreads();
    if (threadIdx.x == 0) {
        for (int i = 1; i < BLK / 64; ++i) lse_combine(m, acc, sm[i], sa[i]);
        float t = -eps * (m + __logf(acc));
        *outp = avg ? 0.5f * (prev + t) : t;
    }
}

// out = mean(ft - f_aa) + mean(gt - g_bb)   (Nx == Ny == B)
__global__ void final_reduce_kernel(const float* __restrict__ ft, const float* __restrict__ faa,
                                    const float* __restrict__ gt, const float* __restrict__ gbb,
                                    float* __restrict__ out, int B) {
    float p = 0.f;
    for (int i = threadIdx.x; i < B; i += BLK)
        p += (ft[i] - faa[i]) + (gt[i] - gbb[i]);
    for (int off = 32; off; off >>= 1) p += __shfl_xor(p, off);
    __shared__ float sp[BLK / 64];
    int lane = threadIdx.x & 63, w = threadIdx.x >> 6;
    if (lane == 0) sp[w] = p;
    __syncthreads();
    if (threadIdx.x == 0) {
        float s = 0.f;
        for (int i = 0; i < BLK / 64; ++i) s += sp[i];
        out[0] = s / (float)B;
    }
}

extern "C" void kernel_launch(void* const* d_in, const int* in_sizes, int n_in,
                              void* d_out, int out_size, void* d_ws, size_t ws_size,
                              hipStream_t stream) {
    const float* pred   = (const float*)d_in[0];
    const float* target = (const float*)d_in[1];
    const int B = in_sizes[1];
    const int K = in_sizes[0] / B;

    float* ws = (float*)d_ws;
    float* x  = ws;            // [B]
    float* s0 = ws + B;        // f,g,faa,gbb (set 0), contiguous 4*B
    float* s1 = ws + 5 * B;    // set 1
    float* bufs[2][4] = {
        { s0, s0 + B, s0 + 2 * B, s0 + 3 * B },
        { s1, s1 + B, s1 + 2 * B, s1 + 3 * B },
    };

    const float logw = -logf((float)B);

    prep_kernel<<<dim3((B + BLK / 64 - 1) / (BLK / 64)), dim3(BLK), 0, stream>>>(
        pred, x, s0, 4 * B, B, K);

    // eps schedule: diameter = K, *0.5 until <= blur, then blur.
    double epsl[64]; int ne = 0;
    double e = (double)K;
    while (e > 0.01 && ne < 62) { epsl[ne++] = e; e *= 0.5; }
    epsl[ne++] = 0.01;

    int cur = 0;
    for (int i = 0; i < ne; ++i) {          // averaged updates
        float eps = (float)epsl[i];
        sink_iter_kernel<<<dim3(4 * B), dim3(BLK), 0, stream>>>(
            x, target,
            bufs[cur][0], bufs[cur][1], bufs[cur][2], bufs[cur][3],
            bufs[cur ^ 1][0], bufs[cur ^ 1][1], bufs[cur ^ 1][2], bufs[cur ^ 1][3],
            B, eps, 1.0f / eps, logw, 1);
        cur ^= 1;
    }
    {   // final non-averaged extrapolation at eps = blur
        float eps = 0.01f;
        sink_iter_kernel<<<dim3(4 * B), dim3(BLK), 0, stream>>>(
            x, target,
            bufs[cur][0], bufs[cur][1], bufs[cur][2], bufs[cur][3],
            bufs[cur ^ 1][0], bufs[cur ^ 1][1], bufs[cur ^ 1][2], bufs[cur ^ 1][3],
            B, eps, 1.0f / eps, logw, 0);
        cur ^= 1;
    }

    final_reduce_kernel<<<dim3(1), dim3(BLK), 0, stream>>>(
        bufs[cur][0], bufs[cur][2], bufs[cur][1], bufs[cur][3],
        (float*)d_out, B);
}